// Round 6
// baseline (275.805 us; speedup 1.0000x reference)
//
#include <hip/hip_runtime.h>
#include <hip/hip_bf16.h>

#define S_STEPS 64

typedef __bf16 bf16x8 __attribute__((ext_vector_type(8)));
typedef float  f32x4  __attribute__((ext_vector_type(4)));
typedef int    i32x4  __attribute__((ext_vector_type(4)));

// ---- async 16B global->LDS (wave-uniform base + lane*16 contiguous dest) ----
__device__ __forceinline__ void async16(const void* g, void* l) {
    __builtin_amdgcn_global_load_lds((const __attribute__((address_space(1))) void*)g,
                                     (__attribute__((address_space(3))) void*)l,
                                     16, 0, 0);
}

// ---------------- encoder (T-parallel) — unchanged ----------------
__global__ void snn_encoder_tp(const float4* __restrict__ xv, ushort4* __restrict__ r,
                               int B, int T, int F4) {
    const int f4i = threadIdx.x & 63;
    const int tc  = threadIdx.x >> 6;           // 0..3
    const int b   = blockIdx.y;
    const int f4  = blockIdx.x * 64 + f4i;
    __shared__ int4 red[4][64];

    int c0 = 0, c1 = 0, c2 = 0, c3 = 0;
    if (b > 0) {
        const float4* xb = xv + ((size_t)b * T + tc * 32) * F4 + f4;
        const float4* xp = xb - (size_t)T * F4;
        for (int t = 0; t < 32; ++t) {
            float4 a = xb[(size_t)t * F4];
            float4 p = xp[(size_t)t * F4];
            c0 += (__fsub_rn(a.x, p.x) >= 0.2f) ? 1 : 0;
            c1 += (__fsub_rn(a.y, p.y) >= 0.2f) ? 1 : 0;
            c2 += (__fsub_rn(a.z, p.z) >= 0.2f) ? 1 : 0;
            c3 += (__fsub_rn(a.w, p.w) >= 0.2f) ? 1 : 0;
        }
    }
    red[tc][f4i] = int4{c0, c1, c2, c3};
    __syncthreads();
    if (tc == 0) {
        int4 a = red[0][f4i], bb = red[1][f4i], cc = red[2][f4i], dd = red[3][f4i];
        int s0 = a.x + bb.x + cc.x + dd.x;
        int s1 = a.y + bb.y + cc.y + dd.y;
        int s2 = a.z + bb.z + cc.z + dd.z;
        int s3 = a.w + bb.w + cc.w + dd.w;
        ushort4 o;
        o.x = __hip_bfloat16_raw(__float2bfloat16((float)s0 * (1.0f / 128.0f))).x;
        o.y = __hip_bfloat16_raw(__float2bfloat16((float)s1 * (1.0f / 128.0f))).x;
        o.z = __hip_bfloat16_raw(__float2bfloat16((float)s2 * (1.0f / 128.0f))).x;
        o.w = __hip_bfloat16_raw(__float2bfloat16((float)s3 * (1.0f / 128.0f))).x;
        r[(size_t)b * F4 + f4] = o;
    }
}

// ---------------- W0 bf16 3-way split (vec4) — for the small GEMM0 only ----------------
__global__ void split_w0_v4(const float4* __restrict__ W, int n4, ushort4* __restrict__ out) {
    int j = blockIdx.x * blockDim.x + threadIdx.x;
    if (j >= n4) return;
    float4 w = W[j];
    float wv[4] = {w.x, w.y, w.z, w.w};
    unsigned short hv[4], mv[4], lv[4];
    #pragma unroll
    for (int q = 0; q < 4; ++q) {
        __hip_bfloat16 hh = __float2bfloat16(wv[q]);
        float r1 = __fsub_rn(wv[q], __bfloat162float(hh));   // exact
        __hip_bfloat16 mm = __float2bfloat16(r1);
        float r2 = __fsub_rn(r1, __bfloat162float(mm));      // exact
        hv[q] = __hip_bfloat16_raw(hh).x;
        mv[q] = __hip_bfloat16_raw(mm).x;
        lv[q] = __hip_bfloat16_raw(__float2bfloat16(r2)).x;
    }
    out[j]          = ushort4{hv[0], hv[1], hv[2], hv[3]};
    out[j + n4]     = ushort4{mv[0], mv[1], mv[2], mv[3]};
    out[j + 2 * n4] = ushort4{lv[0], lv[1], lv[2], lv[3]};
}

// ---------------- W1/W2 i8 fixed-point 3-digit quantizer (vec4) ----------------
__global__ void quant_w_i8(const float4* __restrict__ Wa, const float4* __restrict__ Wb,
                           int na4, int nb4,
                           char4* __restrict__ outA, char4* __restrict__ outB) {
    int i = blockIdx.x * blockDim.x + threadIdx.x;
    const float4* W; char4* out; int n4; int j = i;
    if (j < na4) { W = Wa; out = outA; n4 = na4; }
    else {
        j -= na4;
        if (j >= nb4) return;
        W = Wb; out = outB; n4 = nb4;
    }
    float4 w = W[j];
    float wv[4] = {w.x, w.y, w.z, w.w};
    signed char d2v[4], d1v[4], d0v[4];
    #pragma unroll
    for (int q = 0; q < 4; ++q) {
        int e  = __float2int_rn(wv[q] * 134217728.0f);       // w * 2^27
        int d0 = (int)(signed char)(e & 0xff);
        int e1 = (e - d0) >> 8;                              // exact
        int d1 = (int)(signed char)(e1 & 0xff);
        int d2 = (e1 - d1) >> 8;                             // exact, in [-64,64]
        d0v[q] = (signed char)d0;
        d1v[q] = (signed char)d1;
        d2v[q] = (signed char)d2;
    }
    out[j]          = make_char4(d2v[0], d2v[1], d2v[2], d2v[3]);
    out[j + n4]     = make_char4(d1v[0], d1v[1], d1v[2], d1v[3]);
    out[j + 2 * n4] = make_char4(d0v[0], d0v[1], d0v[2], d0v[3]);
}

// Swizzled staging map (per 16-row x 64-byte group = 64 slots x 16B):
//   slot s holds global (row = s>>2, chunk16B = ((s&3)+(s>>2)+(s>>4)) & 3)
//   frag read slot(rho,kap) = 4*rho + ((kap - rho - (rho>>2)) & 3)
//
// B-MAJOR M-LAYOUT: GEMM M-row index = b*64 + s.  Each wave's 64-row tile is one
// batch element b with all 64 time steps -> LIF scan fused in the epilogue.
// acc[i][j][r] holds s = i*16 + kap*4 + r (seg = i*4+kap), col = j*16 + (lane&15).

// ======== i8 GEMM 128x128 + fused LIF, wave 64x64, 4 blocks/CU ========
// F32OUT=0: spikes i8, rows b*64+s (feeds next i8 GEMM)
// F32OUT=1: spikes f32 [S, Bsz, N] (final output)
template<bool F32OUT>
__global__ __launch_bounds__(256, 4)
void snn_gemm_i8_lif(const signed char* __restrict__ A,
                     const signed char* __restrict__ Wq,
                     const float* __restrict__ bias,
                     signed char* __restrict__ Sout,
                     float* __restrict__ Dout,
                     int M, int N, int K, int Bsz) {
    __shared__ __align__(16) char As[2 * 8192];
    __shared__ __align__(16) char Bs[2 * 8192];
    const int t    = threadIdx.x;
    const int wave = t >> 6;
    const int lane = t & 63;

    int m_idx, n_idx;
    {
        int gx = gridDim.x, gy = gridDim.y;
        int flat = blockIdx.y * gx + blockIdx.x;
        if ((gy & 7) == 0) {
            int x = flat & 7, local = flat >> 3, h = gy >> 3;
            m_idx = x * h + (local % h);
            n_idx = local / h;
        } else { m_idx = blockIdx.y; n_idx = blockIdx.x; }
    }
    const int m0 = m_idx * 128;
    const int n0 = n_idx * 128;
    const int wm = (wave & 1) * 64;
    const int wn = (wave >> 1) * 64;

    const int srow = lane >> 2;
    const int schk = ((lane & 3) + (lane >> 2) + (lane >> 4)) & 3;
    const int rho  = lane & 15;
    const int kap  = lane >> 4;
    const int foff = ((rho << 2) + ((kap - rho - (rho >> 2)) & 3)) * 16;   // bytes

    const int KT = K >> 6;
    const int NT = 3 * KT;
    const size_t PK = (size_t)N * K;

    size_t aOff[2], bOff[2];
    #pragma unroll
    for (int q = 0; q < 2; ++q) {
        aOff[q] = (size_t)(m0 + (wave * 2 + q) * 16 + srow) * K + schk * 16;
        bOff[q] = (size_t)(n0 + (wave * 2 + q) * 16 + srow) * K + schk * 16;
    }

    i32x4 acc[4][4] = {};
    i32x4 afA[4], afB[4], bLo[2], bHi[2];

    auto stageT = [&](int p, int kt, int bsel) {
        const int kk = kt << 6;
        char* as = As + bsel * 8192;
        char* bs = Bs + bsel * 8192;
        const signed char* Bw = Wq + (size_t)p * PK;
        #pragma unroll
        for (int q = 0; q < 2; ++q) {
            async16(A  + aOff[q] + kk, as + (wave * 2 + q) * 1024 + lane * 16);
            async16(Bw + bOff[q] + kk, bs + (wave * 2 + q) * 1024 + lane * 16);
        }
    };

    int sp = 0, skt = 2;

    auto body = [&](int i, i32x4* afc, i32x4* afn) {
        if (i + 2 < NT) {
            stageT(sp, skt, i & 1);
            if (++skt == KT) { skt = 0; ++sp; }
            asm volatile("s_waitcnt vmcnt(4)" ::: "memory");
        } else {
            asm volatile("s_waitcnt vmcnt(0)" ::: "memory");
        }
        __builtin_amdgcn_s_barrier();
        const char* as = As + ((i + 1) & 1) * 8192;
        const char* bs = Bs + ((i + 1) & 1) * 8192;
        #pragma unroll
        for (int q = 0; q < 4; ++q)
            afn[q] = *(const i32x4*)&as[((wm >> 4) + q) * 1024 + foff];
        #pragma unroll
        for (int q = 0; q < 2; ++q)
            bLo[q] = *(const i32x4*)&bs[((wn >> 4) + q) * 1024 + foff];
        __builtin_amdgcn_sched_barrier(0);
        #pragma unroll
        for (int q = 0; q < 4; ++q)
            #pragma unroll
            for (int j = 0; j < 2; ++j)
                acc[q][2 + j] = __builtin_amdgcn_mfma_i32_16x16x64_i8(afc[q], bHi[j], acc[q][2 + j], 0, 0, 0);
        #pragma unroll
        for (int q = 0; q < 2; ++q)
            bHi[q] = *(const i32x4*)&bs[((wn >> 4) + 2 + q) * 1024 + foff];
        asm volatile("s_waitcnt lgkmcnt(0)" ::: "memory");
        __builtin_amdgcn_sched_barrier(0);
        __builtin_amdgcn_s_barrier();
        if (((i + 1) & (KT - 1)) == 0) {
            #pragma unroll
            for (int q = 0; q < 4; ++q)
                #pragma unroll
                for (int j = 0; j < 4; ++j)
                    acc[q][j] = acc[q][j] * 256;
        }
        #pragma unroll
        for (int q = 0; q < 4; ++q)
            #pragma unroll
            for (int j = 0; j < 2; ++j)
                acc[q][j] = __builtin_amdgcn_mfma_i32_16x16x64_i8(afn[q], bLo[j], acc[q][j], 0, 0, 0);
    };

    stageT(0, 0, 0);
    stageT(0, 1, 1);
    asm volatile("s_waitcnt vmcnt(4)" ::: "memory");
    __builtin_amdgcn_s_barrier();
    {
        const char* as = As;
        const char* bs = Bs;
        #pragma unroll
        for (int q = 0; q < 4; ++q)
            afA[q] = *(const i32x4*)&as[((wm >> 4) + q) * 1024 + foff];
        #pragma unroll
        for (int q = 0; q < 2; ++q) {
            bLo[q] = *(const i32x4*)&bs[((wn >> 4) + q) * 1024 + foff];
            bHi[q] = *(const i32x4*)&bs[((wn >> 4) + 2 + q) * 1024 + foff];
        }
    }
    asm volatile("s_waitcnt lgkmcnt(0)" ::: "memory");
    __builtin_amdgcn_sched_barrier(0);
    __builtin_amdgcn_s_barrier();
    #pragma unroll
    for (int q = 0; q < 4; ++q)
        #pragma unroll
        for (int j = 0; j < 2; ++j)
            acc[q][j] = __builtin_amdgcn_mfma_i32_16x16x64_i8(afA[q], bLo[j], acc[q][j], 0, 0, 0);

    for (int i = 0; i < NT - 2; i += 2) {
        body(i, afA, afB);
        body(i + 1, afB, afA);
    }
    body(NT - 2, afA, afB);
    #pragma unroll
    for (int q = 0; q < 4; ++q)
        #pragma unroll
        for (int j = 0; j < 2; ++j)
            acc[q][2 + j] = __builtin_amdgcn_mfma_i32_16x16x64_i8(afB[q], bHi[j], acc[q][2 + j], 0, 0, 0);

    // ---------- fused LIF epilogue ----------
    const float SCALE = 7.450580596923828e-9f;   // 2^-27
    float bb[4];
    #pragma unroll
    for (int j = 0; j < 4; ++j)
        bb[j] = bias[n0 + wn + j * 16 + (lane & 15)];
    #pragma unroll
    for (int i = 0; i < 4; ++i)
        #pragma unroll
        for (int j = 0; j < 4; ++j) {
            i32x4 v = acc[i][j];
            f32x4 c;
            #pragma unroll
            for (int r = 0; r < 4; ++r)
                c[r] = (float)v[r] * SCALE + bb[j];
            acc[i][j] = __builtin_bit_cast(i32x4, c);
        }
    float mj[4] = {0.f, 0.f, 0.f, 0.f};
    const int b_idx = (m0 + wm) >> 6;
    signed char* So = Sout + (size_t)(m0 + wm) * N;
    #pragma unroll
    for (int seg = 0; seg < 16; ++seg) {
        const int si = seg >> 2, sk = seg & 3;
        const int src = (lane & 15) | (((sk + 3) & 3) << 4);
        #pragma unroll
        for (int j = 0; j < 4; ++j) {
            float tin = __shfl(mj[j], src);
            if (seg > 0 && kap == sk) mj[j] = tin;
        }
        if (kap == sk) {
            #pragma unroll
            for (int j = 0; j < 4; ++j) {
                f32x4 c = __builtin_bit_cast(f32x4, acc[si][j]);
                const int ng = n0 + wn + j * 16 + (lane & 15);
                #pragma unroll
                for (int r = 0; r < 4; ++r) {
                    float rst = (mj[j] > 1.0f) ? 1.0f : 0.0f;
                    mj[j] = __fsub_rn(__fadd_rn(__fmul_rn(0.9f, mj[j]), c[r]), rst);
                    if (F32OUT)
                        Dout[((size_t)(seg * 4 + r) * Bsz + b_idx) * N + ng] = (mj[j] > 1.0f) ? 1.0f : 0.0f;
                    else
                        So[(size_t)(seg * 4 + r) * N + ng] = (mj[j] > 1.0f) ? (signed char)1 : (signed char)0;
                }
            }
        }
    }
}

// ================= bf16 GEMM (3-part split) — kept for the small GEMM0 =================
__global__ __launch_bounds__(256)
void snn_gemm_mfma_n(const __hip_bfloat16* __restrict__ A,
                     const __hip_bfloat16* __restrict__ Whi,
                     const __hip_bfloat16* __restrict__ Wmid,
                     const __hip_bfloat16* __restrict__ Wlo,
                     const float* __restrict__ bias,
                     float* __restrict__ C,
                     int M, int N, int K) {
    __shared__ __align__(16) unsigned short As[128 * 32];
    __shared__ __align__(16) unsigned short Bs[128 * 32];
    const int t    = threadIdx.x;
    const int wave = t >> 6;
    const int lane = t & 63;

    int m_idx = blockIdx.y, n_idx = blockIdx.x;
    const int m0 = m_idx * 128;
    const int n0 = n_idx * 128;
    const int wm = (wave & 1) * 64;
    const int wn = (wave >> 1) * 64;

    const int srow = lane >> 2;
    const int schk = ((lane & 3) + (lane >> 2) + (lane >> 4)) & 3;
    const int rho  = lane & 15;
    const int kap  = lane >> 4;
    const int foff = ((rho << 2) + ((kap - rho - (rho >> 2)) & 3)) * 8;   // shorts

    f32x4 acc[4][4] = {};

    const __hip_bfloat16* parts[3] = {Whi, Wmid, Wlo};
    for (int part = 0; part < 3; ++part) {
        const __hip_bfloat16* Bw = parts[part];
        for (int k0 = 0; k0 < K; k0 += 32) {
            __syncthreads();
            #pragma unroll
            for (int q = 0; q < 2; ++q) {
                int grp = wave * 2 + q;
                async16(A  + (size_t)(m0 + grp * 16 + srow) * K + k0 + schk * 8,
                        &As[grp * 512 + lane * 8]);
                async16(Bw + (size_t)(n0 + grp * 16 + srow) * K + k0 + schk * 8,
                        &Bs[grp * 512 + lane * 8]);
            }
            __syncthreads();

            bf16x8 af[4], bfr[4];
            #pragma unroll
            for (int i = 0; i < 4; ++i) {
                af[i]  = *(const bf16x8*)&As[((wm >> 4) + i) * 512 + foff];
                bfr[i] = *(const bf16x8*)&Bs[((wn >> 4) + i) * 512 + foff];
            }
            #pragma unroll
            for (int i = 0; i < 4; ++i)
                #pragma unroll
                for (int j = 0; j < 4; ++j)
                    acc[i][j] = __builtin_amdgcn_mfma_f32_16x16x32_bf16(af[i], bfr[j], acc[i][j], 0, 0, 0);
        }
    }

    #pragma unroll
    for (int i = 0; i < 4; ++i) {
        int mg = m0 + wm + i * 16 + (lane >> 4) * 4;
        #pragma unroll
        for (int j = 0; j < 4; ++j) {
            int ng = n0 + wn + j * 16 + (lane & 15);
            float bb = bias[ng];
            #pragma unroll
            for (int r = 0; r < 4; ++r)
                C[(size_t)(mg + r) * N + ng] = acc[i][j][r] + bb;
        }
    }
}

// ---------------- LIF layer 0 (broadcast), b-major i8 spike output ----------------
__global__ void snn_lif0_i8_bmaj(const float4* __restrict__ cur, uchar4* __restrict__ spk,
                                 int BH4, int H4) {
    int idx = blockIdx.x * blockDim.x + threadIdx.x;
    if (idx >= BH4) return;
    const int b  = idx / H4;
    const int h4 = idx - b * H4;
    uchar4* out = spk + (size_t)b * S_STEPS * H4 + h4;
    float m0 = 0.0f, m1 = 0.0f, m2 = 0.0f, m3 = 0.0f;
    float4 c = cur[idx];
    for (int s = 0; s < S_STEPS; ++s) {
        float r0 = (m0 > 1.0f) ? 1.0f : 0.0f;
        float r1 = (m1 > 1.0f) ? 1.0f : 0.0f;
        float r2 = (m2 > 1.0f) ? 1.0f : 0.0f;
        float r3 = (m3 > 1.0f) ? 1.0f : 0.0f;
        m0 = __fsub_rn(__fadd_rn(__fmul_rn(0.9f, m0), c.x), r0);
        m1 = __fsub_rn(__fadd_rn(__fmul_rn(0.9f, m1), c.y), r1);
        m2 = __fsub_rn(__fadd_rn(__fmul_rn(0.9f, m2), c.z), r2);
        m3 = __fsub_rn(__fadd_rn(__fmul_rn(0.9f, m3), c.w), r3);
        uchar4 o;
        o.x = (m0 > 1.0f) ? 1 : 0;
        o.y = (m1 > 1.0f) ? 1 : 0;
        o.z = (m2 > 1.0f) ? 1 : 0;
        o.w = (m3 > 1.0f) ? 1 : 0;
        out[(size_t)s * H4] = o;
    }
}

extern "C" void kernel_launch(void* const* d_in, const int* in_sizes, int n_in,
                              void* d_out, int out_size, void* d_ws, size_t ws_size,
                              hipStream_t stream) {
    const float* x  = (const float*)d_in[0];
    const float* W0 = (const float*)d_in[1];
    const float* b0 = (const float*)d_in[2];
    const float* W1 = (const float*)d_in[3];
    const float* b1 = (const float*)d_in[4];
    const float* W2 = (const float*)d_in[5];
    const float* b2 = (const float*)d_in[6];

    const int B = 256, T = 128, F = 512, H1 = 1024, H2 = 1024, H3 = 512;
    const int SB = S_STEPS * B;            // 16384

    // ---- workspace carve-up, all 16B aligned ----
    char* w = (char*)d_ws;
    signed char*    spk0 = (signed char*)w;                 w += (size_t)SB * H1;       // 16.7 MB
    signed char*    spk1 = (signed char*)w;                 w += (size_t)SB * H2;       // 16.7 MB
    __hip_bfloat16* r_bf = (__hip_bfloat16*)w;              w += (size_t)B * F * 2;     // 256 KB
    float*          cur0 = (float*)w;                       w += (size_t)B * H1 * 4;    // 1 MB
    __hip_bfloat16* W0s  = (__hip_bfloat16*)w;              w += (size_t)3 * H1 * F * 2;
    signed char*    W1q  = (signed char*)w;                 w += (size_t)3 * H2 * H1;   // 3 MB
    signed char*    W2q  = (signed char*)w;                 w += (size_t)3 * H3 * H2;   // 1.5 MB

    const int nW0 = H1 * F, nW1 = H2 * H1, nW2 = H3 * H2;

    // W0 -> bf16x3 split (for GEMM0)
    split_w0_v4<<<dim3((nW0 / 4 + 255) / 256), dim3(256), 0, stream>>>(
        (const float4*)W0, nW0 / 4, (ushort4*)W0s);

    // W1, W2 -> i8 fixed-point digits [d2][d1][d0]
    {
        int n4 = (nW1 + nW2) / 4;
        quant_w_i8<<<dim3((n4 + 255) / 256), dim3(256), 0, stream>>>(
            (const float4*)W1, (const float4*)W2, nW1 / 4, nW2 / 4,
            (char4*)W1q, (char4*)W2q);
    }

    // 1. delta encoder -> exact bf16 rates [B, F]
    snn_encoder_tp<<<dim3(F / 4 / 64, B), dim3(256), 0, stream>>>(
        (const float4*)x, (ushort4*)r_bf, B, T, F / 4);

    // 2. cur0 = r @ W0^T + b0   [256 x 1024, K=512]  (bf16x3 path)
    snn_gemm_mfma_n<<<dim3(H1 / 128, B / 128), dim3(256), 0, stream>>>(
        r_bf, W0s, W0s + nW0, W0s + 2 * nW0, b0, cur0, B, H1, F);

    // 3. LIF layer 0 (broadcast) -> spk0 i8, b-major rows b*64+s
    snn_lif0_i8_bmaj<<<dim3(B * H1 / 4 / 256), dim3(256), 0, stream>>>(
        (const float4*)cur0, (uchar4*)spk0, B * H1 / 4, H1 / 4);

    // 4+5. cur1 = spk0 @ W1^T + b1, fused LIF -> spk1 i8 b-major [16384 x 1024, K=1024]
    //      128x128 tile, grid 8x128 = 1024 blocks = 4 blocks/CU
    snn_gemm_i8_lif<false><<<dim3(H2 / 128, SB / 128), dim3(256), 0, stream>>>(
        spk0, W1q, b1, spk1, nullptr, SB, H2, H1, B);

    // 6+7. cur2 = spk1 @ W2^T + b2, fused LIF -> d_out f32 [S, B, H3]
    snn_gemm_i8_lif<true><<<dim3(H3 / 128, SB / 128), dim3(256), 0, stream>>>(
        spk1, W2q, b2, nullptr, (float*)d_out, SB, H3, H2, B);
}

// Round 7
// 258.191 us; speedup vs baseline: 1.0682x; 1.0682x over previous
//
#include <hip/hip_runtime.h>
#include <hip/hip_bf16.h>

#define S_STEPS 64

typedef __bf16 bf16x8 __attribute__((ext_vector_type(8)));
typedef float  f32x4  __attribute__((ext_vector_type(4)));
typedef int    i32x4  __attribute__((ext_vector_type(4)));

// ---- async 16B global->LDS (wave-uniform base + lane*16 contiguous dest) ----
__device__ __forceinline__ void async16(const void* g, void* l) {
    __builtin_amdgcn_global_load_lds((const __attribute__((address_space(1))) void*)g,
                                     (__attribute__((address_space(3))) void*)l,
                                     16, 0, 0);
}

// ---------------- encoder (T-parallel) — unchanged ----------------
__global__ void snn_encoder_tp(const float4* __restrict__ xv, ushort4* __restrict__ r,
                               int B, int T, int F4) {
    const int f4i = threadIdx.x & 63;
    const int tc  = threadIdx.x >> 6;           // 0..3
    const int b   = blockIdx.y;
    const int f4  = blockIdx.x * 64 + f4i;
    __shared__ int4 red[4][64];

    int c0 = 0, c1 = 0, c2 = 0, c3 = 0;
    if (b > 0) {
        const float4* xb = xv + ((size_t)b * T + tc * 32) * F4 + f4;
        const float4* xp = xb - (size_t)T * F4;
        for (int t = 0; t < 32; ++t) {
            float4 a = xb[(size_t)t * F4];
            float4 p = xp[(size_t)t * F4];
            c0 += (__fsub_rn(a.x, p.x) >= 0.2f) ? 1 : 0;
            c1 += (__fsub_rn(a.y, p.y) >= 0.2f) ? 1 : 0;
            c2 += (__fsub_rn(a.z, p.z) >= 0.2f) ? 1 : 0;
            c3 += (__fsub_rn(a.w, p.w) >= 0.2f) ? 1 : 0;
        }
    }
    red[tc][f4i] = int4{c0, c1, c2, c3};
    __syncthreads();
    if (tc == 0) {
        int4 a = red[0][f4i], bb = red[1][f4i], cc = red[2][f4i], dd = red[3][f4i];
        int s0 = a.x + bb.x + cc.x + dd.x;
        int s1 = a.y + bb.y + cc.y + dd.y;
        int s2 = a.z + bb.z + cc.z + dd.z;
        int s3 = a.w + bb.w + cc.w + dd.w;
        ushort4 o;
        o.x = __hip_bfloat16_raw(__float2bfloat16((float)s0 * (1.0f / 128.0f))).x;
        o.y = __hip_bfloat16_raw(__float2bfloat16((float)s1 * (1.0f / 128.0f))).x;
        o.z = __hip_bfloat16_raw(__float2bfloat16((float)s2 * (1.0f / 128.0f))).x;
        o.w = __hip_bfloat16_raw(__float2bfloat16((float)s3 * (1.0f / 128.0f))).x;
        r[(size_t)b * F4 + f4] = o;
    }
}

// ---------------- W0 bf16 3-way split (vec4) — for the small GEMM0 only ----------------
__global__ void split_w0_v4(const float4* __restrict__ W, int n4, ushort4* __restrict__ out) {
    int j = blockIdx.x * blockDim.x + threadIdx.x;
    if (j >= n4) return;
    float4 w = W[j];
    float wv[4] = {w.x, w.y, w.z, w.w};
    unsigned short hv[4], mv[4], lv[4];
    #pragma unroll
    for (int q = 0; q < 4; ++q) {
        __hip_bfloat16 hh = __float2bfloat16(wv[q]);
        float r1 = __fsub_rn(wv[q], __bfloat162float(hh));   // exact
        __hip_bfloat16 mm = __float2bfloat16(r1);
        float r2 = __fsub_rn(r1, __bfloat162float(mm));      // exact
        hv[q] = __hip_bfloat16_raw(hh).x;
        mv[q] = __hip_bfloat16_raw(mm).x;
        lv[q] = __hip_bfloat16_raw(__float2bfloat16(r2)).x;
    }
    out[j]          = ushort4{hv[0], hv[1], hv[2], hv[3]};
    out[j + n4]     = ushort4{mv[0], mv[1], mv[2], mv[3]};
    out[j + 2 * n4] = ushort4{lv[0], lv[1], lv[2], lv[3]};
}

// ---------------- W1/W2 i8 fixed-point 3-digit quantizer (vec4) ----------------
__global__ void quant_w_i8(const float4* __restrict__ Wa, const float4* __restrict__ Wb,
                           int na4, int nb4,
                           char4* __restrict__ outA, char4* __restrict__ outB) {
    int i = blockIdx.x * blockDim.x + threadIdx.x;
    const float4* W; char4* out; int n4; int j = i;
    if (j < na4) { W = Wa; out = outA; n4 = na4; }
    else {
        j -= na4;
        if (j >= nb4) return;
        W = Wb; out = outB; n4 = nb4;
    }
    float4 w = W[j];
    float wv[4] = {w.x, w.y, w.z, w.w};
    signed char d2v[4], d1v[4], d0v[4];
    #pragma unroll
    for (int q = 0; q < 4; ++q) {
        int e  = __float2int_rn(wv[q] * 134217728.0f);       // w * 2^27
        int d0 = (int)(signed char)(e & 0xff);
        int e1 = (e - d0) >> 8;                              // exact
        int d1 = (int)(signed char)(e1 & 0xff);
        int d2 = (e1 - d1) >> 8;                             // exact, in [-64,64]
        d0v[q] = (signed char)d0;
        d1v[q] = (signed char)d1;
        d2v[q] = (signed char)d2;
    }
    out[j]          = make_char4(d2v[0], d2v[1], d2v[2], d2v[3]);
    out[j + n4]     = make_char4(d1v[0], d1v[1], d1v[2], d1v[3]);
    out[j + 2 * n4] = make_char4(d0v[0], d0v[1], d0v[2], d0v[3]);
}

// Swizzled staging map (per 16-row x 64-byte group = 64 slots x 16B):
//   slot s holds global (row = s>>2, chunk16B = ((s&3)+(s>>2)+(s>>4)) & 3)
//   frag read slot(rho,kap) = 4*rho + ((kap - rho - (rho>>2)) & 3)
//
// B-MAJOR M-LAYOUT: GEMM M-row index = b*64 + s; wave's 64-row tile = one batch
// element, LIF scan fused in the epilogue (s = 4*seg + r, seg = i*4 + kap).
//
// TRIPLE-BUFFERED, ONE BARRIER PER TILE: body(i) stages buf (i+2)%3; that
// buffer's last reads (tile i-1, body(i-2)) completed before body(i-2)'s
// lgkmcnt(0), which precedes body(i-1)'s barrier -> overwrite is safe with a
// single barrier per tile.  vmcnt(6/4) keeps next tile's loads in flight.

// ================= i8 GEMM A + fused LIF: block 128x256, wave 64x128 =================
__global__ __launch_bounds__(256, 2)
void snn_gemm_i8_w_lif(const signed char* __restrict__ A,
                       const signed char* __restrict__ Wq,
                       const float* __restrict__ bias,
                       signed char* __restrict__ Sout,   // spikes i8, rows b*64+s
                       int M, int N, int K) {
    __shared__ __align__(16) char As[3 * 8192];    // 3 x 8 groups x 1024B
    __shared__ __align__(16) char Bs[3 * 16384];   // 3 x 16 groups x 1024B
    const int t    = threadIdx.x;
    const int wave = t >> 6;
    const int lane = t & 63;

    int m_idx, n_idx;
    {
        int gx = gridDim.x, gy = gridDim.y;
        int flat = blockIdx.y * gx + blockIdx.x;
        if ((gy & 7) == 0) {
            int x = flat & 7, local = flat >> 3, h = gy >> 3;
            m_idx = x * h + (local % h);
            n_idx = local / h;
        } else { m_idx = blockIdx.y; n_idx = blockIdx.x; }
    }
    const int m0 = m_idx * 128;
    const int n0 = n_idx * 256;
    const int wm = (wave >> 1) * 64;
    const int wn = (wave & 1) * 128;

    const int srow = lane >> 2;
    const int schk = ((lane & 3) + (lane >> 2) + (lane >> 4)) & 3;
    const int rho  = lane & 15;
    const int kap  = lane >> 4;
    const int foff = ((rho << 2) + ((kap - rho - (rho >> 2)) & 3)) * 16;   // bytes

    const int KT = K >> 6;
    const int NT = 3 * KT;
    const size_t PK = (size_t)N * K;

    size_t aOff[2], bOff[4];
    #pragma unroll
    for (int q = 0; q < 2; ++q)
        aOff[q] = (size_t)(m0 + (wave * 2 + q) * 16 + srow) * K + schk * 16;
    #pragma unroll
    for (int q = 0; q < 4; ++q)
        bOff[q] = (size_t)(n0 + (wave * 4 + q) * 16 + srow) * K + schk * 16;

    i32x4 acc[4][8] = {};
    i32x4 afA[4], afB[4], bLo[4], bHi[4];

    auto stageT = [&](int p, int kt, int bsel) {
        const int kk = kt << 6;
        char* as = As + bsel * 8192;
        char* bs = Bs + bsel * 16384;
        #pragma unroll
        for (int q = 0; q < 2; ++q)
            async16(A + aOff[q] + kk, as + (wave * 2 + q) * 1024 + lane * 16);
        const signed char* Bw = Wq + (size_t)p * PK;
        #pragma unroll
        for (int q = 0; q < 4; ++q)
            async16(Bw + bOff[q] + kk, bs + (wave * 4 + q) * 1024 + lane * 16);
    };

    int sp = 0, skt = 2;          // next tile to stage
    int sbuf = 2, rbuf = 1;       // stage buffer (i+2)%3, read buffer (i+1)%3

    auto body = [&](int i, i32x4* afc, i32x4* afn) {
        if (i + 2 < NT) {
            stageT(sp, skt, sbuf);
            if (++skt == KT) { skt = 0; ++sp; }
            asm volatile("s_waitcnt vmcnt(6)" ::: "memory");   // tile i+1 landed
        } else {
            asm volatile("s_waitcnt vmcnt(0)" ::: "memory");
        }
        __builtin_amdgcn_s_barrier();                          // tile i+1 visible
        const char* as = As + rbuf * 8192;
        const char* bs = Bs + rbuf * 16384;
        #pragma unroll
        for (int q = 0; q < 4; ++q)
            afn[q] = *(const i32x4*)&as[((wm >> 4) + q) * 1024 + foff];
        #pragma unroll
        for (int q = 0; q < 4; ++q)
            bLo[q] = *(const i32x4*)&bs[((wn >> 4) + q) * 1024 + foff];
        __builtin_amdgcn_sched_barrier(0);                     // reads issued first
        #pragma unroll
        for (int q = 0; q < 4; ++q)
            #pragma unroll
            for (int j = 0; j < 4; ++j)
                acc[q][4 + j] = __builtin_amdgcn_mfma_i32_16x16x64_i8(afc[q], bHi[j], acc[q][4 + j], 0, 0, 0);
        #pragma unroll
        for (int q = 0; q < 4; ++q)
            bHi[q] = *(const i32x4*)&bs[((wn >> 4) + 4 + q) * 1024 + foff];
        asm volatile("s_waitcnt lgkmcnt(0)" ::: "memory");     // frags of i+1 in regs
        __builtin_amdgcn_sched_barrier(0);
        if (((i + 1) & (KT - 1)) == 0) {                       // Horner fold at part edge
            #pragma unroll
            for (int q = 0; q < 4; ++q)
                #pragma unroll
                for (int j = 0; j < 8; ++j)
                    acc[q][j] = acc[q][j] * 256;
        }
        #pragma unroll
        for (int q = 0; q < 4; ++q)
            #pragma unroll
            for (int j = 0; j < 4; ++j)
                acc[q][j] = __builtin_amdgcn_mfma_i32_16x16x64_i8(afn[q], bLo[j], acc[q][j], 0, 0, 0);
        sbuf = (sbuf == 2) ? 0 : sbuf + 1;
        rbuf = (rbuf == 2) ? 0 : rbuf + 1;
    };

    // prologue: stage tiles 0,1; read tile 0; lo-half of tile 0
    stageT(0, 0, 0);
    stageT(0, 1, 1);
    asm volatile("s_waitcnt vmcnt(6)" ::: "memory");
    __builtin_amdgcn_s_barrier();
    {
        const char* as = As;
        const char* bs = Bs;
        #pragma unroll
        for (int q = 0; q < 4; ++q)
            afA[q] = *(const i32x4*)&as[((wm >> 4) + q) * 1024 + foff];
        #pragma unroll
        for (int q = 0; q < 4; ++q) {
            bLo[q] = *(const i32x4*)&bs[((wn >> 4) + q) * 1024 + foff];
            bHi[q] = *(const i32x4*)&bs[((wn >> 4) + 4 + q) * 1024 + foff];
        }
    }
    asm volatile("s_waitcnt lgkmcnt(0)" ::: "memory");
    __builtin_amdgcn_sched_barrier(0);
    #pragma unroll
    for (int q = 0; q < 4; ++q)
        #pragma unroll
        for (int j = 0; j < 4; ++j)
            acc[q][j] = __builtin_amdgcn_mfma_i32_16x16x64_i8(afA[q], bLo[j], acc[q][j], 0, 0, 0);

    for (int i = 0; i < NT - 2; i += 2) {
        body(i, afA, afB);
        body(i + 1, afB, afA);
    }
    body(NT - 2, afA, afB);
    #pragma unroll
    for (int q = 0; q < 4; ++q)
        #pragma unroll
        for (int j = 0; j < 4; ++j)
            acc[q][4 + j] = __builtin_amdgcn_mfma_i32_16x16x64_i8(afB[q], bHi[j], acc[q][4 + j], 0, 0, 0);

    // ---------- fused LIF epilogue ----------
    const float SCALE = 7.450580596923828e-9f;   // 2^-27
    float bb[8];
    #pragma unroll
    for (int j = 0; j < 8; ++j)
        bb[j] = bias[n0 + wn + j * 16 + (lane & 15)];
    #pragma unroll
    for (int i = 0; i < 4; ++i)
        #pragma unroll
        for (int j = 0; j < 8; ++j) {
            i32x4 v = acc[i][j];
            f32x4 c;
            #pragma unroll
            for (int r = 0; r < 4; ++r)
                c[r] = (float)v[r] * SCALE + bb[j];
            acc[i][j] = __builtin_bit_cast(i32x4, c);
        }
    float mj[8] = {0.f, 0.f, 0.f, 0.f, 0.f, 0.f, 0.f, 0.f};
    signed char* So = Sout + (size_t)(m0 + wm) * N;   // rows b*64 + s
    #pragma unroll
    for (int seg = 0; seg < 16; ++seg) {
        const int si = seg >> 2, sk = seg & 3;
        const int src = (lane & 15) | (((sk + 3) & 3) << 4);
        #pragma unroll
        for (int j = 0; j < 8; ++j) {
            float tin = __shfl(mj[j], src);
            if (seg > 0 && kap == sk) mj[j] = tin;
        }
        if (kap == sk) {
            #pragma unroll
            for (int j = 0; j < 8; ++j) {
                f32x4 c = __builtin_bit_cast(f32x4, acc[si][j]);
                const int ng = n0 + wn + j * 16 + (lane & 15);
                #pragma unroll
                for (int r = 0; r < 4; ++r) {
                    float rst = (mj[j] > 1.0f) ? 1.0f : 0.0f;
                    mj[j] = __fsub_rn(__fadd_rn(__fmul_rn(0.9f, mj[j]), c[r]), rst);
                    So[(size_t)(seg * 4 + r) * N + ng] = (mj[j] > 1.0f) ? (signed char)1 : (signed char)0;
                }
            }
        }
    }
}

// ================= i8 GEMM B + fused LIF -> f32 output: block 128x128, wave 64x64 =====
__global__ __launch_bounds__(256, 2)
void snn_gemm_i8_n_lif(const signed char* __restrict__ A,
                       const signed char* __restrict__ Wq,
                       const float* __restrict__ bias,
                       float* __restrict__ Dout,        // [S, Bsz, N] f32 spikes
                       int M, int N, int K, int Bsz) {
    __shared__ __align__(16) char As[3 * 8192];
    __shared__ __align__(16) char Bs[3 * 8192];
    const int t    = threadIdx.x;
    const int wave = t >> 6;
    const int lane = t & 63;

    int m_idx, n_idx;
    {
        int gx = gridDim.x, gy = gridDim.y;
        int flat = blockIdx.y * gx + blockIdx.x;
        if ((gy & 7) == 0) {
            int x = flat & 7, local = flat >> 3, h = gy >> 3;
            m_idx = x * h + (local % h);
            n_idx = local / h;
        } else { m_idx = blockIdx.y; n_idx = blockIdx.x; }
    }
    const int m0 = m_idx * 128;
    const int n0 = n_idx * 128;
    const int wm = (wave & 1) * 64;
    const int wn = (wave >> 1) * 64;

    const int srow = lane >> 2;
    const int schk = ((lane & 3) + (lane >> 2) + (lane >> 4)) & 3;
    const int rho  = lane & 15;
    const int kap  = lane >> 4;
    const int foff = ((rho << 2) + ((kap - rho - (rho >> 2)) & 3)) * 16;   // bytes

    const int KT = K >> 6;
    const int NT = 3 * KT;
    const size_t PK = (size_t)N * K;

    size_t aOff[2], bOff[2];
    #pragma unroll
    for (int q = 0; q < 2; ++q) {
        aOff[q] = (size_t)(m0 + (wave * 2 + q) * 16 + srow) * K + schk * 16;
        bOff[q] = (size_t)(n0 + (wave * 2 + q) * 16 + srow) * K + schk * 16;
    }

    i32x4 acc[4][4] = {};
    i32x4 afA[4], afB[4], bLo[2], bHi[2];

    auto stageT = [&](int p, int kt, int bsel) {
        const int kk = kt << 6;
        char* as = As + bsel * 8192;
        char* bs = Bs + bsel * 8192;
        const signed char* Bw = Wq + (size_t)p * PK;
        #pragma unroll
        for (int q = 0; q < 2; ++q) {
            async16(A  + aOff[q] + kk, as + (wave * 2 + q) * 1024 + lane * 16);
            async16(Bw + bOff[q] + kk, bs + (wave * 2 + q) * 1024 + lane * 16);
        }
    };

    int sp = 0, skt = 2;
    int sbuf = 2, rbuf = 1;

    auto body = [&](int i, i32x4* afc, i32x4* afn) {
        if (i + 2 < NT) {
            stageT(sp, skt, sbuf);
            if (++skt == KT) { skt = 0; ++sp; }
            asm volatile("s_waitcnt vmcnt(4)" ::: "memory");
        } else {
            asm volatile("s_waitcnt vmcnt(0)" ::: "memory");
        }
        __builtin_amdgcn_s_barrier();
        const char* as = As + rbuf * 8192;
        const char* bs = Bs + rbuf * 8192;
        #pragma unroll
        for (int q = 0; q < 4; ++q)
            afn[q] = *(const i32x4*)&as[((wm >> 4) + q) * 1024 + foff];
        #pragma unroll
        for (int q = 0; q < 2; ++q)
            bLo[q] = *(const i32x4*)&bs[((wn >> 4) + q) * 1024 + foff];
        __builtin_amdgcn_sched_barrier(0);
        #pragma unroll
        for (int q = 0; q < 4; ++q)
            #pragma unroll
            for (int j = 0; j < 2; ++j)
                acc[q][2 + j] = __builtin_amdgcn_mfma_i32_16x16x64_i8(afc[q], bHi[j], acc[q][2 + j], 0, 0, 0);
        #pragma unroll
        for (int q = 0; q < 2; ++q)
            bHi[q] = *(const i32x4*)&bs[((wn >> 4) + 2 + q) * 1024 + foff];
        asm volatile("s_waitcnt lgkmcnt(0)" ::: "memory");
        __builtin_amdgcn_sched_barrier(0);
        if (((i + 1) & (KT - 1)) == 0) {
            #pragma unroll
            for (int q = 0; q < 4; ++q)
                #pragma unroll
                for (int j = 0; j < 4; ++j)
                    acc[q][j] = acc[q][j] * 256;
        }
        #pragma unroll
        for (int q = 0; q < 4; ++q)
            #pragma unroll
            for (int j = 0; j < 2; ++j)
                acc[q][j] = __builtin_amdgcn_mfma_i32_16x16x64_i8(afn[q], bLo[j], acc[q][j], 0, 0, 0);
        sbuf = (sbuf == 2) ? 0 : sbuf + 1;
        rbuf = (rbuf == 2) ? 0 : rbuf + 1;
    };

    stageT(0, 0, 0);
    stageT(0, 1, 1);
    asm volatile("s_waitcnt vmcnt(4)" ::: "memory");
    __builtin_amdgcn_s_barrier();
    {
        const char* as = As;
        const char* bs = Bs;
        #pragma unroll
        for (int q = 0; q < 4; ++q)
            afA[q] = *(const i32x4*)&as[((wm >> 4) + q) * 1024 + foff];
        #pragma unroll
        for (int q = 0; q < 2; ++q) {
            bLo[q] = *(const i32x4*)&bs[((wn >> 4) + q) * 1024 + foff];
            bHi[q] = *(const i32x4*)&bs[((wn >> 4) + 2 + q) * 1024 + foff];
        }
    }
    asm volatile("s_waitcnt lgkmcnt(0)" ::: "memory");
    __builtin_amdgcn_sched_barrier(0);
    #pragma unroll
    for (int q = 0; q < 4; ++q)
        #pragma unroll
        for (int j = 0; j < 2; ++j)
            acc[q][j] = __builtin_amdgcn_mfma_i32_16x16x64_i8(afA[q], bLo[j], acc[q][j], 0, 0, 0);

    for (int i = 0; i < NT - 2; i += 2) {
        body(i, afA, afB);
        body(i + 1, afB, afA);
    }
    body(NT - 2, afA, afB);
    #pragma unroll
    for (int q = 0; q < 4; ++q)
        #pragma unroll
        for (int j = 0; j < 2; ++j)
            acc[q][2 + j] = __builtin_amdgcn_mfma_i32_16x16x64_i8(afB[q], bHi[j], acc[q][2 + j], 0, 0, 0);

    // ---------- fused LIF epilogue -> f32 spikes [S, Bsz, N] ----------
    const float SCALE = 7.450580596923828e-9f;   // 2^-27
    float bb[4];
    #pragma unroll
    for (int j = 0; j < 4; ++j)
        bb[j] = bias[n0 + wn + j * 16 + (lane & 15)];
    #pragma unroll
    for (int i = 0; i < 4; ++i)
        #pragma unroll
        for (int j = 0; j < 4; ++j) {
            i32x4 v = acc[i][j];
            f32x4 c;
            #pragma unroll
            for (int r = 0; r < 4; ++r)
                c[r] = (float)v[r] * SCALE + bb[j];
            acc[i][j] = __builtin_bit_cast(i32x4, c);
        }
    float mj[4] = {0.f, 0.f, 0.f, 0.f};
    const int b_idx = (m0 + wm) >> 6;
    #pragma unroll
    for (int seg = 0; seg < 16; ++seg) {
        const int si = seg >> 2, sk = seg & 3;
        const int src = (lane & 15) | (((sk + 3) & 3) << 4);
        #pragma unroll
        for (int j = 0; j < 4; ++j) {
            float tin = __shfl(mj[j], src);
            if (seg > 0 && kap == sk) mj[j] = tin;
        }
        if (kap == sk) {
            #pragma unroll
            for (int j = 0; j < 4; ++j) {
                f32x4 c = __builtin_bit_cast(f32x4, acc[si][j]);
                const int ng = n0 + wn + j * 16 + (lane & 15);
                #pragma unroll
                for (int r = 0; r < 4; ++r) {
                    float rst = (mj[j] > 1.0f) ? 1.0f : 0.0f;
                    mj[j] = __fsub_rn(__fadd_rn(__fmul_rn(0.9f, mj[j]), c[r]), rst);
                    Dout[((size_t)(seg * 4 + r) * Bsz + b_idx) * N + ng] = (mj[j] > 1.0f) ? 1.0f : 0.0f;
                }
            }
        }
    }
}

// ================= bf16 GEMM (3-part split) — kept for the small GEMM0 =================
__global__ __launch_bounds__(256)
void snn_gemm_mfma_n(const __hip_bfloat16* __restrict__ A,
                     const __hip_bfloat16* __restrict__ Whi,
                     const __hip_bfloat16* __restrict__ Wmid,
                     const __hip_bfloat16* __restrict__ Wlo,
                     const float* __restrict__ bias,
                     float* __restrict__ C,
                     int M, int N, int K) {
    __shared__ __align__(16) unsigned short As[128 * 32];
    __shared__ __align__(16) unsigned short Bs[128 * 32];
    const int t    = threadIdx.x;
    const int wave = t >> 6;
    const int lane = t & 63;

    int m_idx = blockIdx.y, n_idx = blockIdx.x;
    const int m0 = m_idx * 128;
    const int n0 = n_idx * 128;
    const int wm = (wave & 1) * 64;
    const int wn = (wave >> 1) * 64;

    const int srow = lane >> 2;
    const int schk = ((lane & 3) + (lane >> 2) + (lane >> 4)) & 3;
    const int rho  = lane & 15;
    const int kap  = lane >> 4;
    const int foff = ((rho << 2) + ((kap - rho - (rho >> 2)) & 3)) * 8;   // shorts

    f32x4 acc[4][4] = {};

    const __hip_bfloat16* parts[3] = {Whi, Wmid, Wlo};
    for (int part = 0; part < 3; ++part) {
        const __hip_bfloat16* Bw = parts[part];
        for (int k0 = 0; k0 < K; k0 += 32) {
            __syncthreads();
            #pragma unroll
            for (int q = 0; q < 2; ++q) {
                int grp = wave * 2 + q;
                async16(A  + (size_t)(m0 + grp * 16 + srow) * K + k0 + schk * 8,
                        &As[grp * 512 + lane * 8]);
                async16(Bw + (size_t)(n0 + grp * 16 + srow) * K + k0 + schk * 8,
                        &Bs[grp * 512 + lane * 8]);
            }
            __syncthreads();

            bf16x8 af[4], bfr[4];
            #pragma unroll
            for (int i = 0; i < 4; ++i) {
                af[i]  = *(const bf16x8*)&As[((wm >> 4) + i) * 512 + foff];
                bfr[i] = *(const bf16x8*)&Bs[((wn >> 4) + i) * 512 + foff];
            }
            #pragma unroll
            for (int i = 0; i < 4; ++i)
                #pragma unroll
                for (int j = 0; j < 4; ++j)
                    acc[i][j] = __builtin_amdgcn_mfma_f32_16x16x32_bf16(af[i], bfr[j], acc[i][j], 0, 0, 0);
        }
    }

    #pragma unroll
    for (int i = 0; i < 4; ++i) {
        int mg = m0 + wm + i * 16 + (lane >> 4) * 4;
        #pragma unroll
        for (int j = 0; j < 4; ++j) {
            int ng = n0 + wn + j * 16 + (lane & 15);
            float bb = bias[ng];
            #pragma unroll
            for (int r = 0; r < 4; ++r)
                C[(size_t)(mg + r) * N + ng] = acc[i][j][r] + bb;
        }
    }
}

// ---------------- LIF layer 0 (broadcast), b-major i8 spike output ----------------
__global__ void snn_lif0_i8_bmaj(const float4* __restrict__ cur, uchar4* __restrict__ spk,
                                 int BH4, int H4) {
    int idx = blockIdx.x * blockDim.x + threadIdx.x;
    if (idx >= BH4) return;
    const int b  = idx / H4;
    const int h4 = idx - b * H4;
    uchar4* out = spk + (size_t)b * S_STEPS * H4 + h4;
    float m0 = 0.0f, m1 = 0.0f, m2 = 0.0f, m3 = 0.0f;
    float4 c = cur[idx];
    for (int s = 0; s < S_STEPS; ++s) {
        float r0 = (m0 > 1.0f) ? 1.0f : 0.0f;
        float r1 = (m1 > 1.0f) ? 1.0f : 0.0f;
        float r2 = (m2 > 1.0f) ? 1.0f : 0.0f;
        float r3 = (m3 > 1.0f) ? 1.0f : 0.0f;
        m0 = __fsub_rn(__fadd_rn(__fmul_rn(0.9f, m0), c.x), r0);
        m1 = __fsub_rn(__fadd_rn(__fmul_rn(0.9f, m1), c.y), r1);
        m2 = __fsub_rn(__fadd_rn(__fmul_rn(0.9f, m2), c.z), r2);
        m3 = __fsub_rn(__fadd_rn(__fmul_rn(0.9f, m3), c.w), r3);
        uchar4 o;
        o.x = (m0 > 1.0f) ? 1 : 0;
        o.y = (m1 > 1.0f) ? 1 : 0;
        o.z = (m2 > 1.0f) ? 1 : 0;
        o.w = (m3 > 1.0f) ? 1 : 0;
        out[(size_t)s * H4] = o;
    }
}

extern "C" void kernel_launch(void* const* d_in, const int* in_sizes, int n_in,
                              void* d_out, int out_size, void* d_ws, size_t ws_size,
                              hipStream_t stream) {
    const float* x  = (const float*)d_in[0];
    const float* W0 = (const float*)d_in[1];
    const float* b0 = (const float*)d_in[2];
    const float* W1 = (const float*)d_in[3];
    const float* b1 = (const float*)d_in[4];
    const float* W2 = (const float*)d_in[5];
    const float* b2 = (const float*)d_in[6];

    const int B = 256, T = 128, F = 512, H1 = 1024, H2 = 1024, H3 = 512;
    const int SB = S_STEPS * B;            // 16384

    // ---- workspace carve-up, all 16B aligned ----
    char* w = (char*)d_ws;
    signed char*    spk0 = (signed char*)w;                 w += (size_t)SB * H1;       // 16.7 MB
    signed char*    spk1 = (signed char*)w;                 w += (size_t)SB * H2;       // 16.7 MB
    __hip_bfloat16* r_bf = (__hip_bfloat16*)w;              w += (size_t)B * F * 2;     // 256 KB
    float*          cur0 = (float*)w;                       w += (size_t)B * H1 * 4;    // 1 MB
    __hip_bfloat16* W0s  = (__hip_bfloat16*)w;              w += (size_t)3 * H1 * F * 2;
    signed char*    W1q  = (signed char*)w;                 w += (size_t)3 * H2 * H1;   // 3 MB
    signed char*    W2q  = (signed char*)w;                 w += (size_t)3 * H3 * H2;   // 1.5 MB

    const int nW0 = H1 * F, nW1 = H2 * H1, nW2 = H3 * H2;

    // W0 -> bf16x3 split (for GEMM0)
    split_w0_v4<<<dim3((nW0 / 4 + 255) / 256), dim3(256), 0, stream>>>(
        (const float4*)W0, nW0 / 4, (ushort4*)W0s);

    // W1, W2 -> i8 fixed-point digits [d2][d1][d0]
    {
        int n4 = (nW1 + nW2) / 4;
        quant_w_i8<<<dim3((n4 + 255) / 256), dim3(256), 0, stream>>>(
            (const float4*)W1, (const float4*)W2, nW1 / 4, nW2 / 4,
            (char4*)W1q, (char4*)W2q);
    }

    // 1. delta encoder -> exact bf16 rates [B, F]
    snn_encoder_tp<<<dim3(F / 4 / 64, B), dim3(256), 0, stream>>>(
        (const float4*)x, (ushort4*)r_bf, B, T, F / 4);

    // 2. cur0 = r @ W0^T + b0   [256 x 1024, K=512]  (bf16x3 path)
    snn_gemm_mfma_n<<<dim3(H1 / 128, B / 128), dim3(256), 0, stream>>>(
        r_bf, W0s, W0s + nW0, W0s + 2 * nW0, b0, cur0, B, H1, F);

    // 3. LIF layer 0 (broadcast) -> spk0 i8, b-major rows b*64+s
    snn_lif0_i8_bmaj<<<dim3(B * H1 / 4 / 256), dim3(256), 0, stream>>>(
        (const float4*)cur0, (uchar4*)spk0, B * H1 / 4, H1 / 4);

    // 4+5. cur1 = spk0 @ W1^T + b1, fused LIF -> spk1 i8 b-major [16384 x 1024, K=1024]
    snn_gemm_i8_w_lif<<<dim3(H2 / 256, SB / 128), dim3(256), 0, stream>>>(
        spk0, W1q, b1, spk1, SB, H2, H1);

    // 6+7. cur2 = spk1 @ W2^T + b2, fused LIF -> d_out f32 [S, B, H3]
    snn_gemm_i8_n_lif<<<dim3(H3 / 128, SB / 128), dim3(256), 0, stream>>>(
        spk1, W2q, b2, (float*)d_out, SB, H3, H2, B);
}